// Round 9
// baseline (86.790 us; speedup 1.0000x reference)
//
#include <hip/hip_runtime.h>
#include <cstdint>
#include <cstddef>

typedef __attribute__((ext_vector_type(8))) short bf16x8;
typedef __attribute__((ext_vector_type(4))) float f32x4;
typedef __attribute__((ext_vector_type(2))) float f32x2;
typedef __attribute__((ext_vector_type(2))) unsigned int u32x2;

static constexpr int BROWS = 262144;
static constexpr int DIM   = 64;
static constexpr int NC    = 256;
static constexpr int OUTD  = 18;
static constexpr int BM    = 32;     // rows per chunk (quarter LDS -> 4 blocks/CU)
static constexpr int NBLK  = 1024;
static constexpr int NCH   = BROWS / BM / NBLK;  // 8

__device__ __forceinline__ unsigned cvt_pk_bf16(float a, float b) {
  unsigned r;
  asm("v_cvt_pk_bf16_f32 %0, %1, %2" : "=v"(r) : "v"(a), "v"(b));
  return r;
}

union U4 { unsigned u[4]; bf16x8 v; };

// pack 8 f32 -> 8 bf16 (RN), order-preserving
__device__ __forceinline__ bf16x8 pack8(const float* s) {
  U4 r;
#pragma unroll
  for (int p = 0; p < 4; ++p) r.u[p] = cvt_pk_bf16(s[2*p], s[2*p+1]);
  return r.v;
}

// split 8 f32 into bf16 hi + bf16 lo (lo = RN_bf16(x - hi))
__device__ __forceinline__ void split8(const float* s, bf16x8& hi, bf16x8& lo) {
  U4 h, l;
#pragma unroll
  for (int p = 0; p < 4; ++p) {
    float a = s[2*p], b = s[2*p+1];
    unsigned ph = cvt_pk_bf16(a, b);
    float ah = __uint_as_float(ph << 16);
    float bh = __uint_as_float(ph & 0xffff0000u);
    h.u[p] = ph;
    l.u[p] = cvt_pk_bf16(a - ah, b - bh);
  }
  hi = h.v; lo = l.v;
}

__global__ __launch_bounds__(512, 8) void rbf_fused(
    const float* __restrict__ x,  const float* __restrict__ Wr,
    const float* __restrict__ br, const float* __restrict__ Wl,
    const float* __restrict__ bl, float* __restrict__ out)
{
  // x split once per chunk: hi/lo bf16, 16B-chunk XOR-swizzled by (row&7). 4 KB each.
  __shared__ __align__(16) unsigned short xhi[BM * DIM];
  __shared__ __align__(16) unsigned short xlo[BM * DIM];
  // feat: bf16 bits, XOR-swizzled 16B chunks (proven R3/R4/R6 layout). 16 KB.
  __shared__ __align__(16) unsigned short feat[BM * NC];
  // wlds: W_lin rows 0..17 bf16 (raw — R6 semantics). 9 KB.
  __shared__ __align__(16) unsigned short wlds[OUTD * NC];

  const int tid  = threadIdx.x;
  const int wav  = tid >> 6;      // 0..7
  const int lane = tid & 63;
  const int li   = lane & 15;
  const int g    = lane >> 4;

  const float S1 = 0.22507907903927651f;  // sqrt(2)/(2*pi): proj in revolutions
  const float SC = 0.08838834764831845f;  // sqrt(2/256), applied to feat (R6 semantics)

  // ---- stage W_lin -> LDS (bf16, swizzled). Verbatim R6. ----
  for (int idx = tid; idx < OUTD * 32; idx += 512) {
    const int r = idx >> 5, c = idx & 31;
    f32x4 v0 = *(const f32x4*)(Wl + r*NC + 8*c);
    f32x4 v1 = *(const f32x4*)(Wl + r*NC + 8*c + 4);
    float v[8];
    v[0]=v0.x; v[1]=v0.y; v[2]=v0.z; v[3]=v0.w;
    v[4]=v1.x; v[5]=v1.y; v[6]=v1.z; v[7]=v1.w;
    *(bf16x8*)(&wlds[r*NC + 8*(c ^ (r & 7))]) = pack8(v);
  }

  // ---- hoist A1 = (S1 * W_rbf)^T tile fragments, hi/lo.  nt = 2*wav + q ----
  bf16x8 a1h[2][2], a1l[2][2];
#pragma unroll
  for (int q = 0; q < 2; ++q) {
    const int n = 16 * (2*wav + q) + li;      // component index
#pragma unroll
    for (int kb = 0; kb < 2; ++kb) {
      float v[8];
#pragma unroll
      for (int j = 0; j < 8; ++j)
        v[j] = Wr[(size_t)(32*kb + 8*g + j) * NC + n] * S1;
      split8(v, a1h[q][kb], a1l[q][kb]);
    }
  }
  f32x4 brf[2];
#pragma unroll
  for (int q = 0; q < 2; ++q)
    brf[q] = *(const f32x4*)(br + 16*(2*wav + q) + 4*g);

  const f32x4 bl0 = *(const f32x4*)(bl + 4*g);   // o = 4g..4g+3 <= 15 < 18
  const float bl16 = bl[16], bl17 = bl[17];
  const int rowc = (li < 2) ? (16 + li) : li;    // t=1 A2 row (dummy rows harmless)

  asm volatile("s_waitcnt lgkmcnt(0)" ::: "memory");
  __builtin_amdgcn_s_barrier();
  asm volatile("" ::: "memory");

  const int sr = tid >> 4;   // staging row 0..31
  const int g4 = tid & 15;   // staging 4-float granule 0..15
  const int cbase = blockIdx.x * NCH;

  for (int i = 0; i < NCH; ++i) {
    const int R = (cbase + i) * BM;

    // ---- stage: load x once (f32x4/thread), split once -> xhi/xlo LDS.
    // 8B writes; same 16B-chunk XOR swizzle as R6 (chunk c16 = (g4>>1)^(sr&7)). ----
    {
      const float* xp = x + ((size_t)R + sr) * DIM + 4*g4;
      f32x4 p = *(const f32x4*)xp;
      unsigned ph0 = cvt_pk_bf16(p.x, p.y);
      unsigned ph1 = cvt_pk_bf16(p.z, p.w);
      float ax = __uint_as_float(ph0 << 16), ay = __uint_as_float(ph0 & 0xffff0000u);
      float az = __uint_as_float(ph1 << 16), aw = __uint_as_float(ph1 & 0xffff0000u);
      unsigned pl0 = cvt_pk_bf16(p.x - ax, p.y - ay);
      unsigned pl1 = cvt_pk_bf16(p.z - az, p.w - aw);
      const int offs = sr*DIM + 8*((g4 >> 1) ^ (sr & 7)) + 4*(g4 & 1);
      *(u32x2*)(&xhi[offs]) = u32x2{ph0, ph1};
      *(u32x2*)(&xlo[offs]) = u32x2{pl0, pl1};
    }
    asm volatile("s_waitcnt lgkmcnt(0)" ::: "memory");
    __builtin_amdgcn_s_barrier();
    asm volatile("" ::: "memory");

    // ---- P1: proj^T tiles = A1 x B(x^T from LDS), 3-pass hi/lo; cos; feat -> LDS.
    // Math verbatim R6. ----
#pragma unroll
    for (int rt = 0; rt < 2; ++rt) {
      const int rr = rt*16 + li;
      const int m  = li & 7;                   // == rr&7
      bf16x8 bh[2], blo_[2];
#pragma unroll
      for (int kb = 0; kb < 2; ++kb) {
        const int slot = 8*((4*kb + g) ^ m);
        bh[kb]   = *(const bf16x8*)(&xhi[rr*DIM + slot]);
        blo_[kb] = *(const bf16x8*)(&xlo[rr*DIM + slot]);
      }
      f32x4 acc[2];
#pragma unroll
      for (int q = 0; q < 2; ++q) acc[q] = f32x4{0.f, 0.f, 0.f, 0.f};
#pragma unroll
      for (int kb = 0; kb < 2; ++kb) {
#pragma unroll
        for (int q = 0; q < 2; ++q) {
          acc[q] = __builtin_amdgcn_mfma_f32_16x16x32_bf16(a1h[q][kb], bh[kb],   acc[q], 0, 0, 0);
          acc[q] = __builtin_amdgcn_mfma_f32_16x16x32_bf16(a1l[q][kb], bh[kb],   acc[q], 0, 0, 0);
          acc[q] = __builtin_amdgcn_mfma_f32_16x16x32_bf16(a1h[q][kb], blo_[kb], acc[q], 0, 0, 0);
        }
      }
      // rev = proj + b_rbf; feat = cos(2*pi*rev)*SC, bf16, packed 8B write. Verbatim R6.
#pragma unroll
      for (int q = 0; q < 2; ++q) {
        float c4[4];
#pragma unroll
        for (int j = 0; j < 4; ++j) {
          float rev = acc[q][j] + brf[q][j];
          float f   = rev - floorf(rev);                 // [0,1) revolutions
          c4[j] = __builtin_amdgcn_cosf(f) * SC;
        }
        u32x2 pk;
        pk.x = cvt_pk_bf16(c4[0], c4[1]);
        pk.y = cvt_pk_bf16(c4[2], c4[3]);
        const int nt   = 2*wav + q;
        const int slot = (2*nt + (g >> 1)) ^ m;          // 16B-chunk XOR swizzle
        *(u32x2*)(&feat[rr*256 + slot*8 + (g & 1)*4]) = pk;
      }
    }
    asm volatile("s_waitcnt lgkmcnt(0)" ::: "memory");
    __builtin_amdgcn_s_barrier();
    asm volatile("" ::: "memory");

    // ---- P2: waves 0..1, rows 0..31. Verbatim R6 body. ----
    if (wav < 2) {
      const int rr = wav*16 + li;               // rows 0..31, 16 per wave
      const int m  = li & 7;                    // == rr&7
      f32x4 acc0 = f32x4{0.f,0.f,0.f,0.f};
      f32x4 acc1 = f32x4{0.f,0.f,0.f,0.f};
#pragma unroll
      for (int kb = 0; kb < 8; ++kb) {
        bf16x8 b2  = *(const bf16x8*)(&feat[rr*256 + (((4*kb + g) ^ m) * 8)]);
        bf16x8 a20 = *(const bf16x8*)(&wlds[li  *NC + 8*((4*kb + g) ^ (li   & 7))]);
        bf16x8 a21 = *(const bf16x8*)(&wlds[rowc*NC + 8*((4*kb + g) ^ (rowc & 7))]);
        acc0 = __builtin_amdgcn_mfma_f32_16x16x32_bf16(a20, b2, acc0, 0, 0, 0);
        acc1 = __builtin_amdgcn_mfma_f32_16x16x32_bf16(a21, b2, acc1, 0, 0, 0);
      }
      float* op = out + (size_t)(R + rr) * OUTD;
      f32x2 s0; s0.x = acc0.x + bl0.x; s0.y = acc0.y + bl0.y;
      f32x2 s1; s1.x = acc0.z + bl0.z; s1.y = acc0.w + bl0.w;
      *(f32x2*)(op + 4*g)     = s0;   // o = 4g..4g+3 (all < 16)
      *(f32x2*)(op + 4*g + 2) = s1;
      if (g == 0) {                   // o = 16,17
        f32x2 s2; s2.x = acc1.x + bl16; s2.y = acc1.y + bl17;
        *(f32x2*)(op + 16) = s2;
      }
    }
    asm volatile("s_waitcnt lgkmcnt(0)" ::: "memory");
    __builtin_amdgcn_s_barrier();
    asm volatile("" ::: "memory");
  }
}

extern "C" void kernel_launch(void* const* d_in, const int* in_sizes, int n_in,
                              void* d_out, int out_size, void* d_ws, size_t ws_size,
                              hipStream_t stream) {
  (void)in_sizes; (void)n_in; (void)d_ws; (void)ws_size; (void)out_size;
  const float* x  = (const float*)d_in[0];
  const float* Wr = (const float*)d_in[1];
  const float* br = (const float*)d_in[2];
  const float* Wl = (const float*)d_in[3];
  const float* bl = (const float*)d_in[4];
  rbf_fused<<<NBLK, 512, 0, stream>>>(x, Wr, br, Wl, bl, (float*)d_out);
}

// Round 10
// 43.251 us; speedup vs baseline: 2.0067x; 2.0067x over previous
//
#include <hip/hip_runtime.h>
#include <cstdint>
#include <cstddef>

typedef __attribute__((ext_vector_type(8))) short bf16x8;
typedef __attribute__((ext_vector_type(4))) float f32x4;
typedef __attribute__((ext_vector_type(2))) float f32x2;
typedef __attribute__((ext_vector_type(2))) unsigned int u32x2;

static constexpr int BROWS = 262144;
static constexpr int DIM   = 64;
static constexpr int NC    = 256;
static constexpr int OUTD  = 18;
static constexpr int BM    = 32;     // rows per chunk (small LDS -> 4 blocks/CU)
static constexpr int NBLK  = 1024;
static constexpr int NCH   = BROWS / BM / NBLK;  // 8

__device__ __forceinline__ unsigned cvt_pk_bf16(float a, float b) {
  unsigned r;
  asm("v_cvt_pk_bf16_f32 %0, %1, %2" : "=v"(r) : "v"(a), "v"(b));
  return r;
}

union U4 { unsigned u[4]; bf16x8 v; };

// pack 8 f32 -> 8 bf16 (RN), order-preserving
__device__ __forceinline__ bf16x8 pack8(const float* s) {
  U4 r;
#pragma unroll
  for (int p = 0; p < 4; ++p) r.u[p] = cvt_pk_bf16(s[2*p], s[2*p+1]);
  return r.v;
}

// split 8 f32 into bf16 hi + bf16 lo (lo = RN_bf16(x - hi))
__device__ __forceinline__ void split8(const float* s, bf16x8& hi, bf16x8& lo) {
  U4 h, l;
#pragma unroll
  for (int p = 0; p < 4; ++p) {
    float a = s[2*p], b = s[2*p+1];
    unsigned ph = cvt_pk_bf16(a, b);
    float ah = __uint_as_float(ph << 16);
    float bh = __uint_as_float(ph & 0xffff0000u);
    h.u[p] = ph;
    l.u[p] = cvt_pk_bf16(a - ah, b - bh);
  }
  hi = h.v; lo = l.v;
}

// NOTE (gfx950): __launch_bounds__(512, 8) forces a 32-VGPR cap -> scratch
// spill (R9: FETCH 191MB, WRITE 106MB, 86us). Declare 4; natural VGPR ~60
// (<=64) already allows 8 waves/SIMD by HW occupancy (waves/CU = 2048/VGPR).
__global__ __launch_bounds__(512, 4) void rbf_fused(
    const float* __restrict__ x,  const float* __restrict__ Wr,
    const float* __restrict__ br, const float* __restrict__ Wl,
    const float* __restrict__ bl, float* __restrict__ out)
{
  // x split once per chunk: hi/lo bf16, 16B-chunk XOR-swizzled by (row&7). 4 KB each.
  __shared__ __align__(16) unsigned short xhi[BM * DIM];
  __shared__ __align__(16) unsigned short xlo[BM * DIM];
  // feat: bf16 bits, XOR-swizzled 16B chunks (proven R3/R4/R6 layout). 16 KB.
  __shared__ __align__(16) unsigned short feat[BM * NC];
  // wlds: W_lin rows 0..17 bf16 (raw — R6 semantics). 9 KB.
  __shared__ __align__(16) unsigned short wlds[OUTD * NC];

  const int tid  = threadIdx.x;
  const int wav  = tid >> 6;      // 0..7
  const int lane = tid & 63;
  const int li   = lane & 15;
  const int g    = lane >> 4;

  const float S1 = 0.22507907903927651f;  // sqrt(2)/(2*pi): proj in revolutions
  const float SC = 0.08838834764831845f;  // sqrt(2/256), applied to feat (R6 semantics)

  // ---- stage W_lin -> LDS (bf16, swizzled). Verbatim R6. ----
  for (int idx = tid; idx < OUTD * 32; idx += 512) {
    const int r = idx >> 5, c = idx & 31;
    f32x4 v0 = *(const f32x4*)(Wl + r*NC + 8*c);
    f32x4 v1 = *(const f32x4*)(Wl + r*NC + 8*c + 4);
    float v[8];
    v[0]=v0.x; v[1]=v0.y; v[2]=v0.z; v[3]=v0.w;
    v[4]=v1.x; v[5]=v1.y; v[6]=v1.z; v[7]=v1.w;
    *(bf16x8*)(&wlds[r*NC + 8*(c ^ (r & 7))]) = pack8(v);
  }

  // ---- hoist A1 = (S1 * W_rbf)^T tile fragments, hi/lo.  nt = 2*wav + q ----
  bf16x8 a1h[2][2], a1l[2][2];
#pragma unroll
  for (int q = 0; q < 2; ++q) {
    const int n = 16 * (2*wav + q) + li;      // component index
#pragma unroll
    for (int kb = 0; kb < 2; ++kb) {
      float v[8];
#pragma unroll
      for (int j = 0; j < 8; ++j)
        v[j] = Wr[(size_t)(32*kb + 8*g + j) * NC + n] * S1;
      split8(v, a1h[q][kb], a1l[q][kb]);
    }
  }
  f32x4 brf[2];
#pragma unroll
  for (int q = 0; q < 2; ++q)
    brf[q] = *(const f32x4*)(br + 16*(2*wav + q) + 4*g);

  const f32x4 bl0 = *(const f32x4*)(bl + 4*g);   // o = 4g..4g+3 <= 15 < 18
  const float bl16 = bl[16], bl17 = bl[17];
  const int rowc = (li < 2) ? (16 + li) : li;    // t=1 A2 row (dummy rows harmless)

  asm volatile("s_waitcnt lgkmcnt(0)" ::: "memory");
  __builtin_amdgcn_s_barrier();
  asm volatile("" ::: "memory");

  const int sr = tid >> 4;   // staging row 0..31
  const int g4 = tid & 15;   // staging 4-float granule 0..15
  const int cbase = blockIdx.x * NCH;

  for (int i = 0; i < NCH; ++i) {
    const int R = (cbase + i) * BM;

    // ---- stage: load x once (f32x4/thread), split once -> xhi/xlo LDS.
    // 8B writes; same 16B-chunk XOR swizzle as R6 (chunk c16 = (g4>>1)^(sr&7)). ----
    {
      const float* xp = x + ((size_t)R + sr) * DIM + 4*g4;
      f32x4 p = *(const f32x4*)xp;
      unsigned ph0 = cvt_pk_bf16(p.x, p.y);
      unsigned ph1 = cvt_pk_bf16(p.z, p.w);
      float ax = __uint_as_float(ph0 << 16), ay = __uint_as_float(ph0 & 0xffff0000u);
      float az = __uint_as_float(ph1 << 16), aw = __uint_as_float(ph1 & 0xffff0000u);
      unsigned pl0 = cvt_pk_bf16(p.x - ax, p.y - ay);
      unsigned pl1 = cvt_pk_bf16(p.z - az, p.w - aw);
      const int offs = sr*DIM + 8*((g4 >> 1) ^ (sr & 7)) + 4*(g4 & 1);
      *(u32x2*)(&xhi[offs]) = u32x2{ph0, ph1};
      *(u32x2*)(&xlo[offs]) = u32x2{pl0, pl1};
    }
    asm volatile("s_waitcnt lgkmcnt(0)" ::: "memory");
    __builtin_amdgcn_s_barrier();
    asm volatile("" ::: "memory");

    // ---- P1: proj^T tiles = A1 x B(x^T from LDS), 3-pass hi/lo; cos; feat -> LDS.
    // Math verbatim R6. ----
#pragma unroll
    for (int rt = 0; rt < 2; ++rt) {
      const int rr = rt*16 + li;
      const int m  = li & 7;                   // == rr&7
      bf16x8 bh[2], blo_[2];
#pragma unroll
      for (int kb = 0; kb < 2; ++kb) {
        const int slot = 8*((4*kb + g) ^ m);
        bh[kb]   = *(const bf16x8*)(&xhi[rr*DIM + slot]);
        blo_[kb] = *(const bf16x8*)(&xlo[rr*DIM + slot]);
      }
      f32x4 acc[2];
#pragma unroll
      for (int q = 0; q < 2; ++q) acc[q] = f32x4{0.f, 0.f, 0.f, 0.f};
#pragma unroll
      for (int kb = 0; kb < 2; ++kb) {
#pragma unroll
        for (int q = 0; q < 2; ++q) {
          acc[q] = __builtin_amdgcn_mfma_f32_16x16x32_bf16(a1h[q][kb], bh[kb],   acc[q], 0, 0, 0);
          acc[q] = __builtin_amdgcn_mfma_f32_16x16x32_bf16(a1l[q][kb], bh[kb],   acc[q], 0, 0, 0);
          acc[q] = __builtin_amdgcn_mfma_f32_16x16x32_bf16(a1h[q][kb], blo_[kb], acc[q], 0, 0, 0);
        }
      }
      // rev = proj + b_rbf; feat = cos(2*pi*rev)*SC, bf16, packed 8B write. Verbatim R6.
#pragma unroll
      for (int q = 0; q < 2; ++q) {
        float c4[4];
#pragma unroll
        for (int j = 0; j < 4; ++j) {
          float rev = acc[q][j] + brf[q][j];
          float f   = rev - floorf(rev);                 // [0,1) revolutions
          c4[j] = __builtin_amdgcn_cosf(f) * SC;
        }
        u32x2 pk;
        pk.x = cvt_pk_bf16(c4[0], c4[1]);
        pk.y = cvt_pk_bf16(c4[2], c4[3]);
        const int nt   = 2*wav + q;
        const int slot = (2*nt + (g >> 1)) ^ m;          // 16B-chunk XOR swizzle
        *(u32x2*)(&feat[rr*256 + slot*8 + (g & 1)*4]) = pk;
      }
    }
    asm volatile("s_waitcnt lgkmcnt(0)" ::: "memory");
    __builtin_amdgcn_s_barrier();
    asm volatile("" ::: "memory");

    // ---- P2: waves 0..1, rows 0..31. Verbatim R6 body. ----
    if (wav < 2) {
      const int rr = wav*16 + li;               // rows 0..31, 16 per wave
      const int m  = li & 7;                    // == rr&7
      f32x4 acc0 = f32x4{0.f,0.f,0.f,0.f};
      f32x4 acc1 = f32x4{0.f,0.f,0.f,0.f};
#pragma unroll
      for (int kb = 0; kb < 8; ++kb) {
        bf16x8 b2  = *(const bf16x8*)(&feat[rr*256 + (((4*kb + g) ^ m) * 8)]);
        bf16x8 a20 = *(const bf16x8*)(&wlds[li  *NC + 8*((4*kb + g) ^ (li   & 7))]);
        bf16x8 a21 = *(const bf16x8*)(&wlds[rowc*NC + 8*((4*kb + g) ^ (rowc & 7))]);
        acc0 = __builtin_amdgcn_mfma_f32_16x16x32_bf16(a20, b2, acc0, 0, 0, 0);
        acc1 = __builtin_amdgcn_mfma_f32_16x16x32_bf16(a21, b2, acc1, 0, 0, 0);
      }
      float* op = out + (size_t)(R + rr) * OUTD;
      f32x2 s0; s0.x = acc0.x + bl0.x; s0.y = acc0.y + bl0.y;
      f32x2 s1; s1.x = acc0.z + bl0.z; s1.y = acc0.w + bl0.w;
      *(f32x2*)(op + 4*g)     = s0;   // o = 4g..4g+3 (all < 16)
      *(f32x2*)(op + 4*g + 2) = s1;
      if (g == 0) {                   // o = 16,17
        f32x2 s2; s2.x = acc1.x + bl16; s2.y = acc1.y + bl17;
        *(f32x2*)(op + 16) = s2;
      }
    }
    asm volatile("s_waitcnt lgkmcnt(0)" ::: "memory");
    __builtin_amdgcn_s_barrier();
    asm volatile("" ::: "memory");
  }
}

extern "C" void kernel_launch(void* const* d_in, const int* in_sizes, int n_in,
                              void* d_out, int out_size, void* d_ws, size_t ws_size,
                              hipStream_t stream) {
  (void)in_sizes; (void)n_in; (void)d_ws; (void)ws_size; (void)out_size;
  const float* x  = (const float*)d_in[0];
  const float* Wr = (const float*)d_in[1];
  const float* br = (const float*)d_in[2];
  const float* Wl = (const float*)d_in[3];
  const float* bl = (const float*)d_in[4];
  rbf_fused<<<NBLK, 512, 0, stream>>>(x, Wr, br, Wl, bl, (float*)d_out);
}

// Round 11
// 39.393 us; speedup vs baseline: 2.2032x; 1.0979x over previous
//
#include <hip/hip_runtime.h>
#include <cstdint>
#include <cstddef>

typedef __attribute__((ext_vector_type(8))) short bf16x8;
typedef __attribute__((ext_vector_type(4))) float f32x4;
typedef __attribute__((ext_vector_type(2))) float f32x2;
typedef __attribute__((ext_vector_type(2))) unsigned int u32x2;

static constexpr int BROWS = 262144;
static constexpr int DIM   = 64;
static constexpr int NC    = 256;
static constexpr int OUTD  = 18;
static constexpr int BM    = 32;     // rows per chunk
static constexpr int NBLK  = 1024;
static constexpr int NCH   = BROWS / BM / NBLK;  // 8

__device__ __forceinline__ unsigned cvt_pk_bf16(float a, float b) {
  unsigned r;
  asm("v_cvt_pk_bf16_f32 %0, %1, %2" : "=v"(r) : "v"(a), "v"(b));
  return r;
}

union U4 { unsigned u[4]; bf16x8 v; };

// pack 8 f32 -> 8 bf16 (RN), order-preserving
__device__ __forceinline__ bf16x8 pack8(const float* s) {
  U4 r;
#pragma unroll
  for (int p = 0; p < 4; ++p) r.u[p] = cvt_pk_bf16(s[2*p], s[2*p+1]);
  return r.v;
}

// split 8 f32 into bf16 hi + bf16 lo (lo = RN_bf16(x - hi))
__device__ __forceinline__ void split8(const float* s, bf16x8& hi, bf16x8& lo) {
  U4 h, l;
#pragma unroll
  for (int p = 0; p < 4; ++p) {
    float a = s[2*p], b = s[2*p+1];
    unsigned ph = cvt_pk_bf16(a, b);
    float ah = __uint_as_float(ph << 16);
    float bh = __uint_as_float(ph & 0xffff0000u);
    h.u[p] = ph;
    l.u[p] = cvt_pk_bf16(a - ah, b - bh);
  }
  hi = h.v; lo = l.v;
}

// NOTE (gfx950): __launch_bounds__(512, 8) forces a 32-VGPR cap -> scratch
// spill (R9). (512,4) observed safe (R10: VGPR 64, no spill).
__global__ __launch_bounds__(512, 4) void rbf_fused(
    const float* __restrict__ x,  const float* __restrict__ Wr,
    const float* __restrict__ br, const float* __restrict__ Wl,
    const float* __restrict__ bl, float* __restrict__ out)
{
  // Ping-pong pipeline buffers. x hi/lo: 4 KB each per buf; feat 16 KB per buf.
  __shared__ __align__(16) unsigned short xhi[2][BM * DIM];
  __shared__ __align__(16) unsigned short xlo[2][BM * DIM];
  __shared__ __align__(16) unsigned short featb[2][BM * NC];
  // wlds: W_lin rows 0..17 bf16 (raw). 9 KB. Total LDS 57 KB -> 2 blocks/CU.
  __shared__ __align__(16) unsigned short wlds[OUTD * NC];

  const int tid  = threadIdx.x;
  const int wav  = tid >> 6;      // 0..7
  const int lane = tid & 63;
  const int li   = lane & 15;
  const int g    = lane >> 4;

  const float S1 = 0.22507907903927651f;  // sqrt(2)/(2*pi): proj in revolutions
  const float SC = 0.08838834764831845f;  // sqrt(2/256), applied to feat

  // ---- stage W_lin -> LDS (bf16, swizzled). Verbatim R6/R10. ----
  for (int idx = tid; idx < OUTD * 32; idx += 512) {
    const int r = idx >> 5, c = idx & 31;
    f32x4 v0 = *(const f32x4*)(Wl + r*NC + 8*c);
    f32x4 v1 = *(const f32x4*)(Wl + r*NC + 8*c + 4);
    float v[8];
    v[0]=v0.x; v[1]=v0.y; v[2]=v0.z; v[3]=v0.w;
    v[4]=v1.x; v[5]=v1.y; v[6]=v1.z; v[7]=v1.w;
    *(bf16x8*)(&wlds[r*NC + 8*(c ^ (r & 7))]) = pack8(v);
  }

  // ---- hoist A1 = (S1 * W_rbf)^T tile fragments, hi/lo.  nt = 2*wav + q ----
  bf16x8 a1h[2][2], a1l[2][2];
#pragma unroll
  for (int q = 0; q < 2; ++q) {
    const int n = 16 * (2*wav + q) + li;      // component index
#pragma unroll
    for (int kb = 0; kb < 2; ++kb) {
      float v[8];
#pragma unroll
      for (int j = 0; j < 8; ++j)
        v[j] = Wr[(size_t)(32*kb + 8*g + j) * NC + n] * S1;
      split8(v, a1h[q][kb], a1l[q][kb]);
    }
  }
  f32x4 brf[2];
#pragma unroll
  for (int q = 0; q < 2; ++q)
    brf[q] = *(const f32x4*)(br + 16*(2*wav + q) + 4*g);

  const f32x4 bl0 = *(const f32x4*)(bl + 4*g);   // o = 4g..4g+3 <= 15 < 18
  const float bl16 = bl[16], bl17 = bl[17];
  const int rowc = (li < 2) ? (16 + li) : li;    // t=1 A2 row (dummy rows harmless)

  const int sr = tid >> 4;   // staging row 0..31
  const int g4 = tid & 15;   // staging 4-float granule 0..15
  const int cbase = blockIdx.x * NCH;

  // stage-write helper (verbatim R10 math): split f32x4 -> hi/lo, 8B writes,
  // 16B-chunk XOR swizzle (chunk c16 = (g4>>1)^(sr&7)).
  auto stage_write = [&](int p, f32x4 v) {
    unsigned ph0 = cvt_pk_bf16(v.x, v.y);
    unsigned ph1 = cvt_pk_bf16(v.z, v.w);
    float ax = __uint_as_float(ph0 << 16), ay = __uint_as_float(ph0 & 0xffff0000u);
    float az = __uint_as_float(ph1 << 16), aw = __uint_as_float(ph1 & 0xffff0000u);
    unsigned pl0 = cvt_pk_bf16(v.x - ax, v.y - ay);
    unsigned pl1 = cvt_pk_bf16(v.z - az, v.w - aw);
    const int offs = sr*DIM + 8*((g4 >> 1) ^ (sr & 7)) + 4*(g4 & 1);
    *(u32x2*)(&xhi[p][offs]) = u32x2{ph0, ph1};
    *(u32x2*)(&xlo[p][offs]) = u32x2{pl0, pl1};
  };

  // prologue: stage chunk 0 into buf 0 (also covers wlds/a1 init sync)
  {
    const float* xp = x + ((size_t)cbase * BM + sr) * DIM + 4*g4;
    stage_write(0, *(const f32x4*)xp);
  }
  asm volatile("s_waitcnt lgkmcnt(0)" ::: "memory");
  __builtin_amdgcn_s_barrier();
  asm volatile("" ::: "memory");

  for (int i = 0; i < NCH; ++i) {
    const int pb = i & 1;
    const int R  = (cbase + i) * BM;

    // ---- S1a: issue next chunk's x loads early (latency hides under P1) ----
    f32x4 pnext;
    const bool havenext = (i + 1 < NCH);
    if (havenext) {
      const float* xp = x + ((size_t)(R + BM) + sr) * DIM + 4*g4;
      pnext = *(const f32x4*)xp;
    }

    // ---- S1b: P1 on xbuf[pb] -> featb[pb]. Math verbatim R10. ----
#pragma unroll
    for (int rt = 0; rt < 2; ++rt) {
      const int rr = rt*16 + li;
      const int m  = li & 7;                   // == rr&7
      bf16x8 bh[2], blo_[2];
#pragma unroll
      for (int kb = 0; kb < 2; ++kb) {
        const int slot = 8*((4*kb + g) ^ m);
        bh[kb]   = *(const bf16x8*)(&xhi[pb][rr*DIM + slot]);
        blo_[kb] = *(const bf16x8*)(&xlo[pb][rr*DIM + slot]);
      }
      f32x4 acc[2];
#pragma unroll
      for (int q = 0; q < 2; ++q) acc[q] = f32x4{0.f, 0.f, 0.f, 0.f};
#pragma unroll
      for (int kb = 0; kb < 2; ++kb) {
#pragma unroll
        for (int q = 0; q < 2; ++q) {
          acc[q] = __builtin_amdgcn_mfma_f32_16x16x32_bf16(a1h[q][kb], bh[kb],   acc[q], 0, 0, 0);
          acc[q] = __builtin_amdgcn_mfma_f32_16x16x32_bf16(a1l[q][kb], bh[kb],   acc[q], 0, 0, 0);
          acc[q] = __builtin_amdgcn_mfma_f32_16x16x32_bf16(a1h[q][kb], blo_[kb], acc[q], 0, 0, 0);
        }
      }
#pragma unroll
      for (int q = 0; q < 2; ++q) {
        float c4[4];
#pragma unroll
        for (int j = 0; j < 4; ++j) {
          float rev = acc[q][j] + brf[q][j];
          float f   = rev - floorf(rev);                 // [0,1) revolutions
          c4[j] = __builtin_amdgcn_cosf(f) * SC;
        }
        u32x2 pk;
        pk.x = cvt_pk_bf16(c4[0], c4[1]);
        pk.y = cvt_pk_bf16(c4[2], c4[3]);
        const int nt   = 2*wav + q;
        const int slot = (2*nt + (g >> 1)) ^ m;          // 16B-chunk XOR swizzle
        *(u32x2*)(&featb[pb][rr*256 + slot*8 + (g & 1)*4]) = pk;
      }
    }

    // ---- S1c: split + write next chunk's xbuf (other parity) ----
    if (havenext) stage_write(pb ^ 1, pnext);

    // ---- single barrier per chunk ----
    asm volatile("s_waitcnt lgkmcnt(0)" ::: "memory");
    __builtin_amdgcn_s_barrier();
    asm volatile("" ::: "memory");

    // ---- S2: P2 on featb[pb]. Verbatim R10 body. No trailing barrier:
    // per-wave program order puts S2(i) before S1(i+1); B_{i+1} fences the
    // next rewrite of featb[pb]; stage writes opposite-parity xbuf only. ----
    if (wav < 2) {
      const int rr = wav*16 + li;               // rows 0..31, 16 per wave
      const int m  = li & 7;                    // == rr&7
      f32x4 acc0 = f32x4{0.f,0.f,0.f,0.f};
      f32x4 acc1 = f32x4{0.f,0.f,0.f,0.f};
#pragma unroll
      for (int kb = 0; kb < 8; ++kb) {
        bf16x8 b2  = *(const bf16x8*)(&featb[pb][rr*256 + (((4*kb + g) ^ m) * 8)]);
        bf16x8 a20 = *(const bf16x8*)(&wlds[li  *NC + 8*((4*kb + g) ^ (li   & 7))]);
        bf16x8 a21 = *(const bf16x8*)(&wlds[rowc*NC + 8*((4*kb + g) ^ (rowc & 7))]);
        acc0 = __builtin_amdgcn_mfma_f32_16x16x32_bf16(a20, b2, acc0, 0, 0, 0);
        acc1 = __builtin_amdgcn_mfma_f32_16x16x32_bf16(a21, b2, acc1, 0, 0, 0);
      }
      float* op = out + (size_t)(R + rr) * OUTD;
      f32x2 s0; s0.x = acc0.x + bl0.x; s0.y = acc0.y + bl0.y;
      f32x2 s1; s1.x = acc0.z + bl0.z; s1.y = acc0.w + bl0.w;
      *(f32x2*)(op + 4*g)     = s0;   // o = 4g..4g+3 (all < 16)
      *(f32x2*)(op + 4*g + 2) = s1;
      if (g == 0) {                   // o = 16,17
        f32x2 s2; s2.x = acc1.x + bl16; s2.y = acc1.y + bl17;
        *(f32x2*)(op + 16) = s2;
      }
    }
  }
}

extern "C" void kernel_launch(void* const* d_in, const int* in_sizes, int n_in,
                              void* d_out, int out_size, void* d_ws, size_t ws_size,
                              hipStream_t stream) {
  (void)in_sizes; (void)n_in; (void)d_ws; (void)ws_size; (void)out_size;
  const float* x  = (const float*)d_in[0];
  const float* Wr = (const float*)d_in[1];
  const float* br = (const float*)d_in[2];
  const float* Wl = (const float*)d_in[3];
  const float* bl = (const float*)d_in[4];
  rbf_fused<<<NBLK, 512, 0, stream>>>(x, Wr, br, Wl, bl, (float*)d_out);
}

// Round 13
// 35.450 us; speedup vs baseline: 2.4483x; 1.1112x over previous
//
#include <hip/hip_runtime.h>
#include <cstdint>
#include <cstddef>

typedef __attribute__((ext_vector_type(8))) short bf16x8;
typedef __attribute__((ext_vector_type(8))) _Float16 f16x8;
typedef __attribute__((ext_vector_type(4))) float f32x4;
typedef __attribute__((ext_vector_type(2))) float f32x2;
typedef __attribute__((ext_vector_type(2))) unsigned int u32x2;

static constexpr int BROWS = 262144;
static constexpr int DIM   = 64;
static constexpr int NC    = 256;
static constexpr int OUTD  = 18;
static constexpr int BM    = 32;     // rows per chunk
static constexpr int NBLK  = 2048;
static constexpr int NCH   = BROWS / BM / NBLK;  // 4

__device__ __forceinline__ unsigned cvt_pk_bf16(float a, float b) {
  unsigned r;
  asm("v_cvt_pk_bf16_f32 %0, %1, %2" : "=v"(r) : "v"(a), "v"(b));
  return r;
}

union U4 { unsigned u[4]; bf16x8 v; };

// pack 8 f32 -> 8 bf16 (RN), order-preserving
__device__ __forceinline__ bf16x8 pack8(const float* s) {
  U4 r;
#pragma unroll
  for (int p = 0; p < 4; ++p) r.u[p] = cvt_pk_bf16(s[2*p], s[2*p+1]);
  return r.v;
}

// NOTE (gfx950): __launch_bounds__(512, 8) forces a 32-VGPR cap -> scratch
// spill (R9). (512,4) observed safe (R10/R11: VGPR 64, no spill).
__global__ __launch_bounds__(512, 4) void rbf_fused(
    const float* __restrict__ x,  const float* __restrict__ Wr,
    const float* __restrict__ br, const float* __restrict__ Wl,
    const float* __restrict__ bl, float* __restrict__ out)
{
  // GEMM1 in single-pass fp16 (u=2^-11; R12 calibration: bf16-x drop gave
  // 7.8e-3 absmax -> fp16 both-sides ~1e-3 each side, total ~2.5e-3 < 7e-3).
  __shared__ __align__(16) unsigned short xh16[2][BM * DIM];    // x as fp16 bits, 2 x 4 KB
  __shared__ __align__(16) unsigned short featb[2][BM * NC];    // feat bf16 bits, 2 x 16 KB
  // wlds: W_lin rows 0..17 bf16 (raw). 9 KB. Total LDS 49 KB -> 3 blocks/CU.
  __shared__ __align__(16) unsigned short wlds[OUTD * NC];

  const int tid  = threadIdx.x;
  const int wav  = tid >> 6;      // 0..7
  const int lane = tid & 63;
  const int li   = lane & 15;
  const int g    = lane >> 4;

  const float S1 = 0.22507907903927651f;  // sqrt(2)/(2*pi): proj in revolutions
  const float SC = 0.08838834764831845f;  // sqrt(2/256), applied to feat

  // ---- stage W_lin -> LDS (bf16, swizzled). Verbatim R11. ----
  for (int idx = tid; idx < OUTD * 32; idx += 512) {
    const int r = idx >> 5, c = idx & 31;
    f32x4 v0 = *(const f32x4*)(Wl + r*NC + 8*c);
    f32x4 v1 = *(const f32x4*)(Wl + r*NC + 8*c + 4);
    float v[8];
    v[0]=v0.x; v[1]=v0.y; v[2]=v0.z; v[3]=v0.w;
    v[4]=v1.x; v[5]=v1.y; v[6]=v1.z; v[7]=v1.w;
    *(bf16x8*)(&wlds[r*NC + 8*(c ^ (r & 7))]) = pack8(v);
  }

  // ---- hoist A1 = (S1 * W_rbf)^T tile fragments, single fp16.  nt = 2*wav + q ----
  f16x8 a1[2][2];
#pragma unroll
  for (int q = 0; q < 2; ++q) {
    const int n = 16 * (2*wav + q) + li;      // component index
#pragma unroll
    for (int kb = 0; kb < 2; ++kb) {
      f16x8 f;
#pragma unroll
      for (int j = 0; j < 8; ++j)
        f[j] = (_Float16)(Wr[(size_t)(32*kb + 8*g + j) * NC + n] * S1);
      a1[q][kb] = f;
    }
  }
  f32x4 brf[2];
#pragma unroll
  for (int q = 0; q < 2; ++q)
    brf[q] = *(const f32x4*)(br + 16*(2*wav + q) + 4*g);

  const f32x4 bl0 = *(const f32x4*)(bl + 4*g);   // o = 4g..4g+3 <= 15 < 18
  const float bl16 = bl[16], bl17 = bl[17];
  const int rowc = (li < 2) ? (16 + li) : li;    // t=1 A2 row (dummy rows harmless)

  const int sr = tid >> 4;   // staging row 0..31
  const int g4 = tid & 15;   // staging 4-float granule 0..15
  const int cbase = blockIdx.x * NCH;

  // stage-write: f32x4 -> fp16 (RNE), 8B write, 16B-chunk XOR swizzle
  // (chunk c16 = (g4>>1)^(sr&7)) — same layout as R11's xhi.
  auto stage_write = [&](int p, f32x4 v) {
    union { _Float16 h[4]; u32x2 u; } cv;
    cv.h[0] = (_Float16)v.x; cv.h[1] = (_Float16)v.y;
    cv.h[2] = (_Float16)v.z; cv.h[3] = (_Float16)v.w;
    const int offs = sr*DIM + 8*((g4 >> 1) ^ (sr & 7)) + 4*(g4 & 1);
    *(u32x2*)(&xh16[p][offs]) = cv.u;
  };

  // prologue: stage chunk 0 into buf 0 (also covers wlds/a1 init sync)
  {
    const float* xp = x + ((size_t)cbase * BM + sr) * DIM + 4*g4;
    stage_write(0, *(const f32x4*)xp);
  }
  asm volatile("s_waitcnt lgkmcnt(0)" ::: "memory");
  __builtin_amdgcn_s_barrier();
  asm volatile("" ::: "memory");

  for (int i = 0; i < NCH; ++i) {
    const int pb = i & 1;
    const int R  = (cbase + i) * BM;

    // ---- S1a: issue next chunk's x loads early (latency hides under P1) ----
    f32x4 pnext;
    const bool havenext = (i + 1 < NCH);
    if (havenext) {
      const float* xp = x + ((size_t)(R + BM) + sr) * DIM + 4*g4;
      pnext = *(const f32x4*)xp;
    }

    // ---- S1b: P1 on xh16[pb] -> featb[pb]. Single fp16 pass. ----
#pragma unroll
    for (int rt = 0; rt < 2; ++rt) {
      const int rr = rt*16 + li;
      const int m  = li & 7;                   // == rr&7
      f16x8 bh[2];
#pragma unroll
      for (int kb = 0; kb < 2; ++kb) {
        const int slot = 8*((4*kb + g) ^ m);
        bh[kb] = *(const f16x8*)(&xh16[pb][rr*DIM + slot]);
      }
      f32x4 acc[2];
#pragma unroll
      for (int q = 0; q < 2; ++q) acc[q] = f32x4{0.f, 0.f, 0.f, 0.f};
#pragma unroll
      for (int kb = 0; kb < 2; ++kb) {
#pragma unroll
        for (int q = 0; q < 2; ++q)
          acc[q] = __builtin_amdgcn_mfma_f32_16x16x32_f16(a1[q][kb], bh[kb], acc[q], 0, 0, 0);
      }
      // rev = proj + b_rbf; feat = cos(2*pi*rev)*SC, bf16, packed 8B write. Verbatim R11.
#pragma unroll
      for (int q = 0; q < 2; ++q) {
        float c4[4];
#pragma unroll
        for (int j = 0; j < 4; ++j) {
          float rev = acc[q][j] + brf[q][j];
          float f   = rev - floorf(rev);                 // [0,1) revolutions
          c4[j] = __builtin_amdgcn_cosf(f) * SC;
        }
        u32x2 pk;
        pk.x = cvt_pk_bf16(c4[0], c4[1]);
        pk.y = cvt_pk_bf16(c4[2], c4[3]);
        const int nt   = 2*wav + q;
        const int slot = (2*nt + (g >> 1)) ^ m;          // 16B-chunk XOR swizzle
        *(u32x2*)(&featb[pb][rr*256 + slot*8 + (g & 1)*4]) = pk;
      }
    }

    // ---- S1c: write next chunk's xh16 (other parity) ----
    if (havenext) stage_write(pb ^ 1, pnext);

    // ---- single barrier per chunk ----
    asm volatile("s_waitcnt lgkmcnt(0)" ::: "memory");
    __builtin_amdgcn_s_barrier();
    asm volatile("" ::: "memory");

    // ---- S2: P2 on featb[pb]. Verbatim R11 body (bf16). No trailing barrier:
    // per-wave program order puts S2(i) before S1(i+1); B_{i+1} fences the
    // next rewrite of featb[pb]; stage writes opposite-parity xh16 only. ----
    if (wav < 2) {
      const int rr = wav*16 + li;               // rows 0..31, 16 per wave
      const int m  = li & 7;                    // == rr&7
      f32x4 acc0 = f32x4{0.f,0.f,0.f,0.f};
      f32x4 acc1 = f32x4{0.f,0.f,0.f,0.f};
#pragma unroll
      for (int kb = 0; kb < 8; ++kb) {
        bf16x8 b2  = *(const bf16x8*)(&featb[pb][rr*256 + (((4*kb + g) ^ m) * 8)]);
        bf16x8 a20 = *(const bf16x8*)(&wlds[li  *NC + 8*((4*kb + g) ^ (li   & 7))]);
        bf16x8 a21 = *(const bf16x8*)(&wlds[rowc*NC + 8*((4*kb + g) ^ (rowc & 7))]);
        acc0 = __builtin_amdgcn_mfma_f32_16x16x32_bf16(a20, b2, acc0, 0, 0, 0);
        acc1 = __builtin_amdgcn_mfma_f32_16x16x32_bf16(a21, b2, acc1, 0, 0, 0);
      }
      float* op = out + (size_t)(R + rr) * OUTD;
      f32x2 s0; s0.x = acc0.x + bl0.x; s0.y = acc0.y + bl0.y;
      f32x2 s1; s1.x = acc0.z + bl0.z; s1.y = acc0.w + bl0.w;
      *(f32x2*)(op + 4*g)     = s0;   // o = 4g..4g+3 (all < 16)
      *(f32x2*)(op + 4*g + 2) = s1;
      if (g == 0) {                   // o = 16,17
        f32x2 s2; s2.x = acc1.x + bl16; s2.y = acc1.y + bl17;
        *(f32x2*)(op + 16) = s2;
      }
    }
  }
}

extern "C" void kernel_launch(void* const* d_in, const int* in_sizes, int n_in,
                              void* d_out, int out_size, void* d_ws, size_t ws_size,
                              hipStream_t stream) {
  (void)in_sizes; (void)n_in; (void)d_ws; (void)ws_size; (void)out_size;
  const float* x  = (const float*)d_in[0];
  const float* Wr = (const float*)d_in[1];
  const float* br = (const float*)d_in[2];
  const float* Wl = (const float*)d_in[3];
  const float* bl = (const float*)d_in[4];
  rbf_fused<<<NBLK, 512, 0, stream>>>(x, Wr, br, Wl, bl, (float*)d_out);
}

// Round 14
// 33.118 us; speedup vs baseline: 2.6206x; 1.0704x over previous
//
#include <hip/hip_runtime.h>
#include <cstdint>
#include <cstddef>

typedef __attribute__((ext_vector_type(8))) short bf16x8;
typedef __attribute__((ext_vector_type(8))) _Float16 f16x8;
typedef __attribute__((ext_vector_type(4))) float f32x4;
typedef __attribute__((ext_vector_type(2))) float f32x2;
typedef __attribute__((ext_vector_type(2))) unsigned int u32x2;

static constexpr int BROWS = 262144;
static constexpr int DIM   = 64;
static constexpr int NC    = 256;
static constexpr int OUTD  = 18;
static constexpr int BM    = 32;     // rows per chunk
static constexpr int NBLK  = 1024;
static constexpr int NCH   = BROWS / BM / NBLK;  // 8

__device__ __forceinline__ unsigned cvt_pk_bf16(float a, float b) {
  unsigned r;
  asm("v_cvt_pk_bf16_f32 %0, %1, %2" : "=v"(r) : "v"(a), "v"(b));
  return r;
}

union U4 { unsigned u[4]; bf16x8 v; };

// pack 8 f32 -> 8 bf16 (RN), order-preserving
__device__ __forceinline__ bf16x8 pack8(const float* s) {
  U4 r;
#pragma unroll
  for (int p = 0; p < 4; ++p) r.u[p] = cvt_pk_bf16(s[2*p], s[2*p+1]);
  return r.v;
}

// NOTE (gfx950): __launch_bounds__(512, 8) forces a 32-VGPR cap -> scratch
// spill (R9). (512,4) observed safe (R10-R13: VGPR 48-64, no spill).
__global__ __launch_bounds__(512, 4) void rbf_fused(
    const float* __restrict__ x,  const float* __restrict__ Wr,
    const float* __restrict__ br, const float* __restrict__ Wl,
    const float* __restrict__ bl, float* __restrict__ out)
{
  // GEMM1 in single-pass fp16 (R12 calibration: error ~2.5e-3 < 7e-3, and
  // measured absmax stayed at the 1.95e-3 floor in R13).
  __shared__ __align__(16) unsigned short xh16[2][BM * DIM];    // x as fp16 bits, 2 x 4 KB
  __shared__ __align__(16) unsigned short featb[2][BM * NC];    // feat bf16 bits, 2 x 16 KB
  // wlds: W_lin rows 0..17 bf16 (raw). 9 KB. Total LDS 49 KB.
  __shared__ __align__(16) unsigned short wlds[OUTD * NC];

  const int tid  = threadIdx.x;
  const int wav  = tid >> 6;      // 0..7
  const int lane = tid & 63;
  const int li   = lane & 15;
  const int g    = lane >> 4;

  const float S1 = 0.22507907903927651f;  // sqrt(2)/(2*pi): proj in revolutions
  const float SC = 0.08838834764831845f;  // sqrt(2/256), applied to feat

  // ---- stage W_lin -> LDS (bf16, swizzled). Verbatim R11/R13. ----
  for (int idx = tid; idx < OUTD * 32; idx += 512) {
    const int r = idx >> 5, c = idx & 31;
    f32x4 v0 = *(const f32x4*)(Wl + r*NC + 8*c);
    f32x4 v1 = *(const f32x4*)(Wl + r*NC + 8*c + 4);
    float v[8];
    v[0]=v0.x; v[1]=v0.y; v[2]=v0.z; v[3]=v0.w;
    v[4]=v1.x; v[5]=v1.y; v[6]=v1.z; v[7]=v1.w;
    *(bf16x8*)(&wlds[r*NC + 8*(c ^ (r & 7))]) = pack8(v);
  }

  // ---- hoist A1 = (S1 * W_rbf)^T tile fragments, single fp16.  nt = 2*wav + q ----
  f16x8 a1[2][2];
#pragma unroll
  for (int q = 0; q < 2; ++q) {
    const int n = 16 * (2*wav + q) + li;      // component index
#pragma unroll
    for (int kb = 0; kb < 2; ++kb) {
      f16x8 f;
#pragma unroll
      for (int j = 0; j < 8; ++j)
        f[j] = (_Float16)(Wr[(size_t)(32*kb + 8*g + j) * NC + n] * S1);
      a1[q][kb] = f;
    }
  }
  f32x4 brf[2];
#pragma unroll
  for (int q = 0; q < 2; ++q)
    brf[q] = *(const f32x4*)(br + 16*(2*wav + q) + 4*g);

  const f32x4 bl0 = *(const f32x4*)(bl + 4*g);   // o = 4g..4g+3 <= 15 < 18
  const float bl16 = bl[16], bl17 = bl[17];
  const int rowc = (li < 2) ? (16 + li) : li;    // o-tile-1 A2 row (dummy rows harmless)

  const int sr = tid >> 4;   // staging row 0..31
  const int g4 = tid & 15;   // staging 4-float granule 0..15
  const int cbase = blockIdx.x * NCH;

  // stage-write: f32x4 -> fp16 (RNE), 8B write, 16B-chunk XOR swizzle
  // (chunk c16 = (g4>>1)^(sr&7)).
  auto stage_write = [&](int p, f32x4 v) {
    union { _Float16 h[4]; u32x2 u; } cv;
    cv.h[0] = (_Float16)v.x; cv.h[1] = (_Float16)v.y;
    cv.h[2] = (_Float16)v.z; cv.h[3] = (_Float16)v.w;
    const int offs = sr*DIM + 8*((g4 >> 1) ^ (sr & 7)) + 4*(g4 & 1);
    *(u32x2*)(&xh16[p][offs]) = cv.u;
  };

  // prologue: stage chunk 0 into buf 0 (also covers wlds/a1 init sync)
  {
    const float* xp = x + ((size_t)cbase * BM + sr) * DIM + 4*g4;
    stage_write(0, *(const f32x4*)xp);
  }
  asm volatile("s_waitcnt lgkmcnt(0)" ::: "memory");
  __builtin_amdgcn_s_barrier();
  asm volatile("" ::: "memory");

  for (int i = 0; i < NCH; ++i) {
    const int pb = i & 1;
    const int R  = (cbase + i) * BM;

    // ---- S1a: issue next chunk's x loads early (latency hides under P1) ----
    f32x4 pnext;
    const bool havenext = (i + 1 < NCH);
    if (havenext) {
      const float* xp = x + ((size_t)(R + BM) + sr) * DIM + 4*g4;
      pnext = *(const f32x4*)xp;
    }

    // ---- S1b: P1 on xh16[pb] -> featb[pb]. Single fp16 pass. Verbatim R13. ----
#pragma unroll
    for (int rt = 0; rt < 2; ++rt) {
      const int rr = rt*16 + li;
      const int m  = li & 7;                   // == rr&7
      f16x8 bh[2];
#pragma unroll
      for (int kb = 0; kb < 2; ++kb) {
        const int slot = 8*((4*kb + g) ^ m);
        bh[kb] = *(const f16x8*)(&xh16[pb][rr*DIM + slot]);
      }
      f32x4 acc[2];
#pragma unroll
      for (int q = 0; q < 2; ++q) acc[q] = f32x4{0.f, 0.f, 0.f, 0.f};
#pragma unroll
      for (int kb = 0; kb < 2; ++kb) {
#pragma unroll
        for (int q = 0; q < 2; ++q)
          acc[q] = __builtin_amdgcn_mfma_f32_16x16x32_f16(a1[q][kb], bh[kb], acc[q], 0, 0, 0);
      }
      // rev = proj + b_rbf; feat = cos(2*pi*rev)*SC, bf16, packed 8B write.
#pragma unroll
      for (int q = 0; q < 2; ++q) {
        float c4[4];
#pragma unroll
        for (int j = 0; j < 4; ++j) {
          float rev = acc[q][j] + brf[q][j];
          float f   = rev - floorf(rev);                 // [0,1) revolutions
          c4[j] = __builtin_amdgcn_cosf(f) * SC;
        }
        u32x2 pk;
        pk.x = cvt_pk_bf16(c4[0], c4[1]);
        pk.y = cvt_pk_bf16(c4[2], c4[3]);
        const int nt   = 2*wav + q;
        const int slot = (2*nt + (g >> 1)) ^ m;          // 16B-chunk XOR swizzle
        *(u32x2*)(&featb[pb][rr*256 + slot*8 + (g & 1)*4]) = pk;
      }
    }

    // ---- S1c: write next chunk's xh16 (other parity) ----
    if (havenext) stage_write(pb ^ 1, pnext);

    // ---- single barrier per chunk ----
    asm volatile("s_waitcnt lgkmcnt(0)" ::: "memory");
    __builtin_amdgcn_s_barrier();
    asm volatile("" ::: "memory");

    // ---- S2: P2 on featb[pb], spread over 4 waves: wave = (ot, rt2).
    // ot=0: o 0..15 chain; ot=1: o 16..17 chain. Stores disjoint by ot.
    // Same single-barrier hazard structure as R13 (readers drain at the
    // pre-barrier lgkmcnt(0); featb double-buffered). ----
    if (wav < 4) {
      const int rt2 = wav & 1;
      const int ot  = wav >> 1;
      const int rr  = rt2*16 + li;              // rows 0..31
      const int m   = li & 7;                   // == rr&7
      const int arow = (ot == 0) ? li : rowc;
      const int asw  = arow & 7;
      f32x4 acc2 = f32x4{0.f,0.f,0.f,0.f};
#pragma unroll
      for (int kb = 0; kb < 8; ++kb) {
        bf16x8 b2  = *(const bf16x8*)(&featb[pb][rr*256 + (((4*kb + g) ^ m) * 8)]);
        bf16x8 a2f = *(const bf16x8*)(&wlds[arow*NC + 8*((4*kb + g) ^ asw)]);
        acc2 = __builtin_amdgcn_mfma_f32_16x16x32_bf16(a2f, b2, acc2, 0, 0, 0);
      }
      float* op = out + (size_t)(R + rr) * OUTD;
      if (ot == 0) {
        f32x2 s0; s0.x = acc2.x + bl0.x; s0.y = acc2.y + bl0.y;
        f32x2 s1; s1.x = acc2.z + bl0.z; s1.y = acc2.w + bl0.w;
        *(f32x2*)(op + 4*g)     = s0;   // o = 4g..4g+3 (all < 16)
        *(f32x2*)(op + 4*g + 2) = s1;
      } else if (g == 0) {              // o = 16,17
        f32x2 s2; s2.x = acc2.x + bl16; s2.y = acc2.y + bl17;
        *(f32x2*)(op + 16) = s2;
      }
    }
  }
}

extern "C" void kernel_launch(void* const* d_in, const int* in_sizes, int n_in,
                              void* d_out, int out_size, void* d_ws, size_t ws_size,
                              hipStream_t stream) {
  (void)in_sizes; (void)n_in; (void)d_ws; (void)ws_size; (void)out_size;
  const float* x  = (const float*)d_in[0];
  const float* Wr = (const float*)d_in[1];
  const float* br = (const float*)d_in[2];
  const float* Wl = (const float*)d_in[3];
  const float* bl = (const float*)d_in[4];
  rbf_fused<<<NBLK, 512, 0, stream>>>(x, Wr, br, Wl, bl, (float*)d_out);
}